// Round 6
// baseline (4393.710 us; speedup 1.0000x reference)
//
#include <hip/hip_runtime.h>
#include <hip/hip_bf16.h>

// ---------------- problem constants ----------------
constexpr int N_   = 32;
constexpr int C_   = 3;
constexpr int P_   = 14;
constexpr int PHW  = 16;
constexpr int IND  = 768;
constexpr int D_   = 768;
constexpr int NH_  = 12;
constexpr int DH_  = 64;
constexpr int L_   = 12;
constexpr int OUT_ = 1000;
constexpr int S_   = 197;
constexpr int MLP_ = 3072;
constexpr int NPATCH = P_ * P_;      // 196
constexpr int ROWS   = N_ * S_;      // 6304
constexpr int TROWS  = N_ * NPATCH;  // 6272
constexpr int RPAD   = 6400;
constexpr int SP_R   = 256;
constexpr int SP_C   = 224;

typedef __attribute__((ext_vector_type(8))) short bf16x8;
typedef __attribute__((ext_vector_type(4))) float f32x4;

__device__ __forceinline__ float bf2f(ushort u) {
    union { float f; unsigned int i; } v; v.i = ((unsigned int)u) << 16; return v.f;
}
__device__ __forceinline__ ushort f2bf(float f) {
    union { float f; unsigned int i; } v; v.f = f;
    unsigned int r = v.i + 0x7fffu + ((v.i >> 16) & 1u);
    return (ushort)(r >> 16);
}

// =================================================================
// bf16 MFMA GEMM, 2-phase double-buffered pipeline (T3-min + T4).
// A [M,K] bf16 row-major, Bt [N,K] bf16 row-major.
// 128x128 tile, BK=32, 4 waves, each wave 64x64 via 4x4 16x16x32 MFMA.
// batch z: bi=z/inner, bj=z%inner; ptr += bi*off?1 + bj*off?2.
// swz: XCD-bijective remap of (x,y) for L2 A-panel locality.
// vtout: if set and bi==2 (QKV V-section), write transposed to Vt[b][dh][s].
// splitK>1: z = K-split index (batch must be 1); each split computes
//   K/splitK and unsafeAtomicAdd's its fp32 partial into C (bias: split 0).
// =================================================================
__global__ __launch_bounds__(256)
void mfma_gemm(const ushort* __restrict__ Ag,
               const ushort* __restrict__ Bg,
               void* __restrict__ Cg,
               const float* __restrict__ biasg,
               int M, int N, int K,
               int lda, int ldb, int ldc,
               long offA1, long offA2,
               long offB1, long offB2,
               long offC1, long offC2,
               long offS1, long offS2,
               int inner, float alpha, int act, int outbf, int accum,
               int swz, ushort* __restrict__ vtout, int splitK)
{
    const int bz = blockIdx.z;
    const int bi = bz / inner, bj = bz % inner;
    const ushort* A = Ag + bi * offA1 + bj * offA2;
    const ushort* B = Bg + bi * offB1 + bj * offB2;
    const long coff = bi * offC1 + bj * offC2;
    const float* bias = biasg ? (biasg + bi * offS1 + bj * offS2) : nullptr;

    int bx = blockIdx.x, by = blockIdx.y;
    if (swz) {
        const int gx = gridDim.x;
        const int nwg = gx * gridDim.y;
        const int orig = by * gx + bx;
        const int q = nwg >> 3, r = nwg & 7;
        const int xcd = orig & 7, loc = orig >> 3;
        const int wgid = (xcd < r ? xcd * (q + 1) : r * (q + 1) + (xcd - r) * q) + loc;
        bx = wgid % gx;
        by = wgid / gx;
    }

    __shared__ ushort As[2][128 * 32];
    __shared__ ushort Bs[2][128 * 32];

    const int tid  = threadIdx.x;
    const int w    = tid >> 6;
    const int lhi  = (tid & 63) >> 4;
    const int llo  = tid & 15;
    const int wr   = w >> 1, wc = w & 1;
    const int row0 = by * 128;
    const int col0 = bx * 128;

    f32x4 acc[4][4];
#pragma unroll
    for (int m = 0; m < 4; ++m)
#pragma unroll
        for (int n = 0; n < 4; ++n) acc[m][n] = (f32x4){0.f, 0.f, 0.f, 0.f};

    // staging geometry: chunk c = it*256+tid; row=c>>2, slot=c&3.
    // LDS physical (row, slot) holds global (row, slot ^ ((row>>1)&3)).
    const int r0s = tid >> 2,        s0s = tid & 3;
    const int r1s = 64 + (tid >> 2), s1s = tid & 3;
    const int ss0 = s0s ^ ((r0s >> 1) & 3);
    const int ss1 = s1s ^ ((r1s >> 1) & 3);
    const int dst0 = (w << 6) << 3;          // chunk base (ushorts) for load 0
    const int dst1 = (256 + (w << 6)) << 3;  // for load 1

    const long arow0 = (long)(row0 + r0s) * lda + ss0 * 8;
    const long arow1 = (long)(row0 + r1s) * lda + ss1 * 8;
    const long brow0 = (long)(col0 + r0s) * ldb + ss0 * 8;
    const long brow1 = (long)(col0 + r1s) * ldb + ss1 * 8;

    const int kperblk = K / splitK;              // multiple of 32 by construction
    const int kbase   = (splitK > 1) ? bi * kperblk : 0;

#define STAGE(buf, k0)                                                                     \
    do {                                                                                   \
        __builtin_amdgcn_global_load_lds(                                                  \
            (const __attribute__((address_space(1))) void*)(A + arow0 + (k0)),             \
            (__attribute__((address_space(3))) void*)(&As[buf][0] + dst0), 16, 0, 0);      \
        __builtin_amdgcn_global_load_lds(                                                  \
            (const __attribute__((address_space(1))) void*)(A + arow1 + (k0)),             \
            (__attribute__((address_space(3))) void*)(&As[buf][0] + dst1), 16, 0, 0);      \
        __builtin_amdgcn_global_load_lds(                                                  \
            (const __attribute__((address_space(1))) void*)(B + brow0 + (k0)),             \
            (__attribute__((address_space(3))) void*)(&Bs[buf][0] + dst0), 16, 0, 0);      \
        __builtin_amdgcn_global_load_lds(                                                  \
            (const __attribute__((address_space(1))) void*)(B + brow1 + (k0)),             \
            (__attribute__((address_space(3))) void*)(&Bs[buf][0] + dst1), 16, 0, 0);      \
    } while (0)

    const int nt = kperblk >> 5;
    STAGE(0, kbase);
    for (int t = 0; t < nt; ++t) {
        const int cur = t & 1;
        if (t + 1 < nt) {
            STAGE(cur ^ 1, kbase + ((t + 1) << 5));
            asm volatile("s_waitcnt vmcnt(4)" ::: "memory");  // oldest 4 (cur buf) done
        } else {
            asm volatile("s_waitcnt vmcnt(0)" ::: "memory");
        }
        __builtin_amdgcn_s_barrier();       // raw: no implicit drain
        asm volatile("" ::: "memory");

        bf16x8 av[4], bv[4];
#pragma unroll
        for (int m = 0; m < 4; ++m) {
            int R = wr * 64 + m * 16 + llo;
            av[m] = *(const bf16x8*)(&As[cur][0] + R * 32 + ((lhi ^ ((R >> 1) & 3)) << 3));
        }
#pragma unroll
        for (int n = 0; n < 4; ++n) {
            int R = wc * 64 + n * 16 + llo;
            bv[n] = *(const bf16x8*)(&Bs[cur][0] + R * 32 + ((lhi ^ ((R >> 1) & 3)) << 3));
        }
#pragma unroll
        for (int m = 0; m < 4; ++m)
#pragma unroll
            for (int n = 0; n < 4; ++n)
                acc[m][n] = __builtin_amdgcn_mfma_f32_16x16x32_bf16(av[m], bv[n], acc[m][n], 0, 0, 0);

        asm volatile("" ::: "memory");
        __builtin_amdgcn_s_barrier();       // reads of cur done before next STAGE overwrites
    }
#undef STAGE

    // epilogue
    float* Cf = (float*)Cg + coff;
    ushort* Ch = (ushort*)Cg + coff;
    const bool vpath = (vtout != nullptr) && (bi == 2);
#pragma unroll
    for (int m = 0; m < 4; ++m) {
#pragma unroll
        for (int n = 0; n < 4; ++n) {
#pragma unroll
            for (int j = 0; j < 4; ++j) {
                int gr = row0 + wr * 64 + m * 16 + lhi * 4 + j;
                int gc = col0 + wc * 64 + n * 16 + llo;
                if (gr >= M || gc >= N) continue;
                float v = acc[m][n][j] * alpha;
                if (splitK > 1) {
                    if (bias && bi == 0) v += bias[gc];
                    unsafeAtomicAdd(&Cf[(long)gr * ldc + gc], v);
                    continue;
                }
                if (bias) v += bias[gc];
                if (act == 1) v = 0.5f * v * (1.f + erff(v * 0.70710678118654752f));
                if (vpath) {
                    int nn = gr / 197, s = gr - nn * 197;
                    vtout[(((long)nn * NH_ + bj) * 64 + gc) * SP_C + s] = f2bf(v);
                } else {
                    long ci = (long)gr * ldc + gc;
                    if (outbf) {
                        Ch[ci] = f2bf(v);
                    } else {
                        if (accum) v += Cf[ci];
                        Cf[ci] = v;
                    }
                }
            }
        }
    }
}

// ---------------- im2col (patchify) -> bf16 ----------------
__global__ __launch_bounds__(256)
void im2col_kernel(const float* __restrict__ img, ushort* __restrict__ patches)
{
    long idx = (long)blockIdx.x * 256 + threadIdx.x;
    if (idx >= (long)TROWS * IND) return;
    int e = (int)(idx % IND);
    int t = (int)((idx / IND) % NPATCH);
    int n = (int)(idx / ((long)IND * NPATCH));
    int pw = e & 15, ph = (e >> 4) & 15, c = e >> 8;
    int px = t % P_, py = t / P_;
    patches[idx] = f2bf(img[(((long)n * C_ + c) * 224 + py * PHW + ph) * 224 + px * PHW + pw]);
}

// ---------------- assemble x = [cls ; tokens] + pos (fp32) ----------------
__global__ __launch_bounds__(256)
void assemble_kernel(const float* __restrict__ tokens,
                     const float* __restrict__ cls,
                     const float* __restrict__ pos,
                     float* __restrict__ x)
{
    long idx = (long)blockIdx.x * 256 + threadIdx.x;
    if (idx >= (long)ROWS * D_) return;
    int d = (int)(idx % D_);
    int s = (int)((idx / D_) % S_);
    long n = idx / ((long)D_ * S_);
    float v = (s == 0) ? cls[d] : tokens[((long)n * NPATCH + (s - 1)) * D_ + d];
    x[idx] = v + pos[(long)s * D_ + d];
}

// ---------------- layernorm fp32 -> bf16 ----------------
__global__ __launch_bounds__(256)
void layernorm_kernel(const float* __restrict__ x, ushort* __restrict__ out,
                      const float* __restrict__ g, const float* __restrict__ b)
{
    long row = blockIdx.x;
    const float* xr = x + row * D_;
    ushort* orow = out + row * D_;
    int tid = threadIdx.x;
    float v0 = xr[tid], v1 = xr[tid + 256], v2 = xr[tid + 512];
    float s  = v0 + v1 + v2;
    float sq = v0 * v0 + v1 * v1 + v2 * v2;
    for (int off = 32; off > 0; off >>= 1) {
        s  += __shfl_down(s, off);
        sq += __shfl_down(sq, off);
    }
    __shared__ float rs[4], rq[4];
    int wave = tid >> 6, lane = tid & 63;
    if (lane == 0) { rs[wave] = s; rq[wave] = sq; }
    __syncthreads();
    float S  = rs[0] + rs[1] + rs[2] + rs[3];
    float SQ = rq[0] + rq[1] + rq[2] + rq[3];
    float mean = S * (1.f / 768.f);
    float var  = SQ * (1.f / 768.f) - mean * mean;
    float rstd = rsqrtf(var + 1e-5f);
    orow[tid]       = f2bf((v0 - mean) * rstd * g[tid]       + b[tid]);
    orow[tid + 256] = f2bf((v1 - mean) * rstd * g[tid + 256] + b[tid + 256]);
    orow[tid + 512] = f2bf((v2 - mean) * rstd * g[tid + 512] + b[tid + 512]);
}

// ---------------- softmax over 197, 4 rows per block, zero-pad to 224 ----------------
__global__ __launch_bounds__(256)
void softmax197_kernel(ushort* __restrict__ scores)
{
    long rid = (long)blockIdx.x * 4 + (threadIdx.x >> 6);
    if (rid >= (long)N_ * NH_ * S_) return;
    long batch = rid / S_;
    long r = rid % S_;
    ushort* p = scores + (batch * SP_R + r) * SP_C;
    int lane = threadIdx.x & 63;
    float v[4];
    float mx = -INFINITY;
#pragma unroll
    for (int i = 0; i < 4; ++i) {
        int idx = lane + i * 64;
        v[i] = (idx < S_) ? bf2f(p[idx]) : -INFINITY;
        mx = fmaxf(mx, v[i]);
    }
    for (int off = 32; off > 0; off >>= 1) mx = fmaxf(mx, __shfl_xor(mx, off));
    float sum = 0.f;
#pragma unroll
    for (int i = 0; i < 4; ++i) {
        int idx = lane + i * 64;
        if (idx < S_) { v[i] = expf(v[i] - mx); sum += v[i]; }
    }
    for (int off = 32; off > 0; off >>= 1) sum += __shfl_xor(sum, off);
    float inv = 1.f / sum;
#pragma unroll
    for (int i = 0; i < 4; ++i) {
        int idx = lane + i * 64;
        if (idx < SP_C) p[idx] = (idx < S_) ? f2bf(v[i] * inv) : (ushort)0;
    }
}

// ---------------- fp32 [R][C] -> bf16 transposed [C][R], batched over z (layer) ----------------
__global__ __launch_bounds__(256)
void transcast_kernel(const float* __restrict__ in, ushort* __restrict__ out,
                      int R, int C, long inL, long outL)
{
    const float* ip = in + (long)blockIdx.z * inL;
    ushort* op = out + (long)blockIdx.z * outL;
    __shared__ float t[32][33];
    int c0 = blockIdx.x * 32, r0 = blockIdx.y * 32;
    int tx = threadIdx.x & 31, ty = threadIdx.x >> 5;
#pragma unroll
    for (int i = 0; i < 4; ++i) {
        int r = r0 + ty * 4 + i, c = c0 + tx;
        float v = 0.f;
        if (r < R && c < C) v = ip[(long)r * C + c];
        t[ty * 4 + i][tx] = v;
    }
    __syncthreads();
#pragma unroll
    for (int i = 0; i < 4; ++i) {
        int c = c0 + ty * 4 + i, r = r0 + tx;
        if (c < C && r < R) op[(long)c * R + r] = f2bf(t[tx][ty * 4 + i]);
    }
}

// ---------------- fp32 [R][C] -> fp32 transposed [C][R] ----------------
__global__ __launch_bounds__(256)
void transf32_kernel(const float* __restrict__ in, float* __restrict__ out, int R, int C)
{
    __shared__ float t[32][33];
    int c0 = blockIdx.x * 32, r0 = blockIdx.y * 32;
    int tx = threadIdx.x & 31, ty = threadIdx.x >> 5;
#pragma unroll
    for (int i = 0; i < 4; ++i) {
        int r = r0 + ty * 4 + i, c = c0 + tx;
        float v = 0.f;
        if (r < R && c < C) v = in[(long)r * C + c];
        t[ty * 4 + i][tx] = v;
    }
    __syncthreads();
#pragma unroll
    for (int i = 0; i < 4; ++i) {
        int c = c0 + ty * 4 + i, r = r0 + tx;
        if (c < C && r < R) out[(long)c * R + r] = t[tx][ty * 4 + i];
    }
}

// ---------------- compact per-head transposed QKV weights ----------------
// out[z][sec][h][e][d] (bf16), z-layer stride 36*4096 els. Bt[e][d] = W[l][h][d][e].
__global__ __launch_bounds__(256)
void build_wqkvC_kernel(const float* __restrict__ Wq, const float* __restrict__ Wk,
                        const float* __restrict__ Wv, int l0, ushort* __restrict__ out)
{
    long idx = (long)blockIdx.x * 256 + threadIdx.x;
    if (idx >= 36L * 4096) return;
    int z = blockIdx.z, l = l0 + z;
    int sec = (int)(idx / 49152);
    int r   = (int)(idx % 49152);
    int h = r / 4096, rr = r % 4096, e = rr / 64, d = rr % 64;
    const float* W = sec == 0 ? Wq : (sec == 1 ? Wk : Wv);
    out[(long)z * 147456 + idx] = f2bf(W[(((long)l * NH_ + h) * 64 + d) * 64 + e]);
}

// ---------------- all-layer QKV bias: out[l][sec*768 + h*64 + e] ----------------
__global__ __launch_bounds__(256)
void build_bqkv_kernel(const float* __restrict__ bq, const float* __restrict__ bk,
                       const float* __restrict__ bv, float* __restrict__ out)
{
    int i = blockIdx.x * 256 + threadIdx.x;
    if (i >= L_ * 2304) return;
    int l = i / 2304, n = i % 2304;
    int sec = n / 768, h = (n % 768) / 64, e = n % 64;
    const float* b = sec == 0 ? bq : (sec == 1 ? bk : bv);
    out[i] = b[((long)l * NH_ + h) * 64 + e];
}

// ---------------- head: one wave per (n, c) output ----------------
__global__ __launch_bounds__(256)
void head_kernel(const float* __restrict__ x, const float* __restrict__ Wt,
                 const float* __restrict__ bhead, float* __restrict__ logits)
{
    int wid = blockIdx.x * 4 + (threadIdx.x >> 6);
    int lane = threadIdx.x & 63;
    int n = wid / OUT_, c = wid % OUT_;
    if (n >= N_) return;
    const float* xr = x + (long)n * S_ * D_;   // cls row (s=0)
    const float* wr = Wt + (long)c * D_;
    float acc = 0.f;
#pragma unroll
    for (int i = 0; i < 12; ++i) acc += xr[lane + i * 64] * wr[lane + i * 64];
    for (int off = 32; off > 0; off >>= 1) acc += __shfl_down(acc, off);
    if (lane == 0) logits[(long)n * OUT_ + c] = acc + bhead[c];
}

// ---------------- final softmax over 1000 ----------------
__global__ __launch_bounds__(256)
void softmax_out_kernel(const float* __restrict__ logits, float* __restrict__ out)
{
    int row = blockIdx.x;
    int tid = threadIdx.x;
    const float* p = logits + (long)row * OUT_;
    float v[4];
    float mx = -INFINITY;
#pragma unroll
    for (int i = 0; i < 4; ++i) {
        int idx = tid + i * 256;
        v[i] = (idx < OUT_) ? p[idx] : -INFINITY;
        mx = fmaxf(mx, v[i]);
    }
    int wave = tid >> 6, lane = tid & 63;
    for (int off = 32; off > 0; off >>= 1) mx = fmaxf(mx, __shfl_xor(mx, off));
    __shared__ float r1[4], r2[4];
    if (lane == 0) r1[wave] = mx;
    __syncthreads();
    mx = fmaxf(fmaxf(r1[0], r1[1]), fmaxf(r1[2], r1[3]));
    float sum = 0.f;
#pragma unroll
    for (int i = 0; i < 4; ++i) {
        int idx = tid + i * 256;
        if (idx < OUT_) { v[i] = expf(v[i] - mx); sum += v[i]; }
    }
    for (int off = 32; off > 0; off >>= 1) sum += __shfl_xor(sum, off);
    if (lane == 0) r2[wave] = sum;
    __syncthreads();
    sum = r2[0] + r2[1] + r2[2] + r2[3];
    float inv = 1.f / sum;
#pragma unroll
    for (int i = 0; i < 4; ++i) {
        int idx = tid + i * 256;
        if (idx < OUT_) out[(long)row * OUT_ + idx] = v[i] * inv;
    }
}

// ---------------- host driver ----------------
extern "C" void kernel_launch(void* const* d_in, const int* in_sizes, int n_in,
                              void* d_out, int out_size, void* d_ws, size_t ws_size,
                              hipStream_t stream)
{
    const float* images = (const float*)d_in[0];
    const float* W_map  = (const float*)d_in[1];
    const float* b_map  = (const float*)d_in[2];
    const float* cls    = (const float*)d_in[3];
    const float* pos    = (const float*)d_in[4];
    const float* ln1_g  = (const float*)d_in[5];
    const float* ln1_b  = (const float*)d_in[6];
    const float* Wq     = (const float*)d_in[7];
    const float* bq     = (const float*)d_in[8];
    const float* Wk     = (const float*)d_in[9];
    const float* bk     = (const float*)d_in[10];
    const float* Wv     = (const float*)d_in[11];
    const float* bv     = (const float*)d_in[12];
    const float* ln2_g  = (const float*)d_in[13];
    const float* ln2_b  = (const float*)d_in[14];
    const float* W1     = (const float*)d_in[15];
    const float* b1     = (const float*)d_in[16];
    const float* W2     = (const float*)d_in[17];
    const float* b2     = (const float*)d_in[18];
    const float* W_head = (const float*)d_in[19];
    const float* b_head = (const float*)d_in[20];

    char* base = (char*)d_ws;
    float*  x       = (float*)base;   base += 19660800L;   // 6400*768*4
    ushort* hbuf    = (ushort*)base;  base += 9830400L;    // 6400*768*2
    ushort* qkv     = (ushort*)base;  base += 29491200L;   // 6400*2304*2
    ushort* Vt      = (ushort*)base;  base += 11038720L;   // 385*64*224*2 (1 batch slack)
    ushort* scoresP = (ushort*)base;  base += 44040192L;   // 384*256*224*2
    ushort* mbuf    = (ushort*)base;  base += 39321600L;   // 6400*3072*2
    ushort* Wmapt   = (ushort*)base;  base += 1179648L;    // 768*768*2
    float*  bqkvA   = (float*)base;   base += 110592L;     // 12*2304*4
    ushort* WqkvC   = (ushort*)base;  base += 3538944L;    // 12*36*4096*2

    size_t used = (size_t)(base - (char*)d_ws);
    const long W1L_ALL = 56623104L, W2L_ALL = 56623104L;   // 12*3072*768*2 each
    const long W1L_ONE = 4718592L,  W2L_ONE = 4718592L;
    bool hoist = ws_size >= used + (size_t)(W1L_ALL + W2L_ALL);
    ushort* W1tA = (ushort*)base;  base += hoist ? W1L_ALL : W1L_ONE;
    ushort* W2tA = (ushort*)base;  base += hoist ? W2L_ALL : W2L_ONE;
    const long w1str = hoist ? 3072L * 768 : 0;
    const long w2str = hoist ? 768L * 3072 : 0;

    // post-loop aliases into scoresP region
    float* W_headT = (float*)scoresP;                       // 1000*768*4
    float* logits  = (float*)((char*)scoresP + 3072000L);   // 32*1000*4
    // pre-loop aliases
    float*  tokens  = (float*)scoresP;                      // 6272*768*4
    ushort* patches = mbuf;                                 // 6272*768*2

    // ==== one-time preprocessing ====
    build_wqkvC_kernel<<<dim3(576, 1, L_), 256, 0, stream>>>(Wq, Wk, Wv, 0, WqkvC);
    build_bqkv_kernel<<<(L_ * 2304 + 255) / 256, 256, 0, stream>>>(bq, bk, bv, bqkvA);
    transcast_kernel<<<dim3(24, 24, 1), 256, 0, stream>>>(W_map, Wmapt, IND, D_, 0L, 0L);
    if (hoist) {
        transcast_kernel<<<dim3(96, 24, L_), 256, 0, stream>>>(W1, W1tA, D_, MLP_,
                                                               (long)D_ * MLP_, 3072L * 768);
        transcast_kernel<<<dim3(24, 96, L_), 256, 0, stream>>>(W2, W2tA, MLP_, D_,
                                                               (long)MLP_ * D_, 768L * 3072);
    }

    // ==== patch embedding ====
    {
        long tot = (long)TROWS * IND;
        im2col_kernel<<<(int)((tot + 255) / 256), 256, 0, stream>>>(images, patches);
    }
    mfma_gemm<<<dim3(D_ / 128, TROWS / 128, 1), 256, 0, stream>>>(
        patches, Wmapt, tokens, b_map,
        TROWS, D_, IND, IND, IND, D_,
        0L, 0L, 0L, 0L, 0L, 0L, 0L, 0L, 1, 1.f, 0, 0, 0, 1, nullptr, 1);
    {
        long tot = (long)ROWS * D_;
        assemble_kernel<<<(int)((tot + 255) / 256), 256, 0, stream>>>(tokens, cls, pos, x);
    }

    for (int l = 0; l < L_; ++l) {
        layernorm_kernel<<<ROWS, 256, 0, stream>>>(x, hbuf, ln1_g + (long)l * D_, ln1_b + (long)l * D_);

        // QKV compact batched: z = sec*12 + h; M=6304, N=64, K=64.
        // sec==2 (V) writes transposed straight into Vt (pads multiply by softmax zeros).
        mfma_gemm<<<dim3(1, RPAD / 128, 36), 256, 0, stream>>>(
            hbuf, WqkvC + (long)l * 147456, qkv, bqkvA + (long)l * 2304,
            ROWS, 64, 64, D_, 64, 2304,
            0L, 64L,
            12L * 4096, 4096L,
            768L, 64L,
            768L, 64L,
            12, 1.f, 0, 1, 0, 0, Vt, 1);

        // scores = Q @ K^T / 8 -> bf16 [batch][256][224]
        mfma_gemm<<<dim3(2, 2, N_ * NH_), 256, 0, stream>>>(
            qkv, qkv + 768, scoresP, nullptr,
            S_, S_, DH_, 2304, 2304, SP_C,
            (long)S_ * 2304, 64L, (long)S_ * 2304, 64L,
            (long)NH_ * SP_R * SP_C, (long)SP_R * SP_C, 0L, 0L,
            NH_, 0.125f, 0, 1, 0, 0, nullptr, 1);

        softmax197_kernel<<<(N_ * NH_ * S_ + 3) / 4, 256, 0, stream>>>(scoresP);

        // x += P @ V   (per (n,h); heads own disjoint columns)
        mfma_gemm<<<dim3(1, 2, N_ * NH_), 256, 0, stream>>>(
            scoresP, Vt, x, nullptr,
            S_, DH_, SP_C, SP_C, SP_C, D_,
            (long)NH_ * SP_R * SP_C, (long)SP_R * SP_C,
            (long)NH_ * 64 * SP_C, (long)64 * SP_C,
            (long)S_ * D_, 64L, 0L, 0L,
            NH_, 1.f, 0, 0, 1, 0, nullptr, 1);

        layernorm_kernel<<<ROWS, 256, 0, stream>>>(x, hbuf, ln2_g + (long)l * D_, ln2_b + (long)l * D_);

        // MLP1: m = gelu(h @ W1 + b1) -> bf16  (1200 blocks, fine)
        if (!hoist)
            transcast_kernel<<<dim3(96, 24, 1), 256, 0, stream>>>(
                W1 + (long)l * D_ * MLP_, W1tA, D_, MLP_, 0L, 0L);
        mfma_gemm<<<dim3(MLP_ / 128, RPAD / 128, 1), 256, 0, stream>>>(
            hbuf, W1tA + (long)l * w1str, mbuf, b1 + (long)l * MLP_,
            ROWS, MLP_, D_, D_, D_, MLP_,
            0L, 0L, 0L, 0L, 0L, 0L, 0L, 0L, 1, 1.f, 1, 1, 0, 1, nullptr, 1);

        // MLP2: x += m @ W2 + b2 — split-K=4 (300 -> 1200 blocks), atomic fp32 partials
        if (!hoist)
            transcast_kernel<<<dim3(24, 96, 1), 256, 0, stream>>>(
                W2 + (long)l * MLP_ * D_, W2tA, MLP_, D_, 0L, 0L);
        mfma_gemm<<<dim3(D_ / 128, RPAD / 128, 4), 256, 0, stream>>>(
            mbuf, W2tA + (long)l * w2str, x, b2 + (long)l * D_,
            ROWS, D_, MLP_, MLP_, MLP_, D_,
            0L, 0L, 0L, 0L, 0L, 0L, 0L, 0L, 1, 1.f, 0, 0, 1, 1, nullptr, 4);
    }

    // ==== head: logits = x[:,0,:] @ W_head + b_head, then softmax ====
    transf32_kernel<<<dim3(32, 24), 256, 0, stream>>>(W_head, W_headT, D_, OUT_);
    head_kernel<<<(N_ * OUT_) / 4, 256, 0, stream>>>(x, W_headT, b_head, logits);
    softmax_out_kernel<<<N_, 256, 0, stream>>>(logits, (float*)d_out);
}